// Round 10
// baseline (79.354 us; speedup 1.0000x reference)
//
#include <hip/hip_runtime.h>
#include <stdint.h>

#define T 16
#define NB 8
#define NROI 20000
#define NA 5
#define MM (NROI + NA)   // 20005
#define MMPAD 20224      // NBLK*256, per-(img,a) ov stride
#define RPI 128
#define FGPI 32
#define NBLK 79          // blocks per image in k_iou
#define SORTCAP 32768
#define FGCAP 2048       // LDS fg sort capacity
#define BGCAP 8192       // LDS bg sort capacity

// ---------------- threefry2x32 (JAX-exact, 20 rounds), host+device ----------------
__host__ __device__ __forceinline__ void tf2x32(uint32_t k0, uint32_t k1,
                                                uint32_t x0, uint32_t x1,
                                                uint32_t& o0, uint32_t& o1) {
  uint32_t ks2 = k0 ^ k1 ^ 0x1BD11BDAu;
  x0 += k0; x1 += k1;
#define ROUND(r) { x0 += x1; x1 = (x1 << (r)) | (x1 >> (32 - (r))); x1 ^= x0; }
  ROUND(13) ROUND(15) ROUND(26) ROUND(6)
  x0 += k1; x1 += ks2 + 1u;
  ROUND(17) ROUND(29) ROUND(16) ROUND(24)
  x0 += ks2; x1 += k0 + 2u;
  ROUND(13) ROUND(15) ROUND(26) ROUND(6)
  x0 += k0; x1 += k1 + 3u;
  ROUND(17) ROUND(29) ROUND(16) ROUND(24)
  x0 += k1; x1 += ks2 + 4u;
  ROUND(13) ROUND(15) ROUND(26) ROUND(6)
  x0 += ks2; x1 += k0 + 5u;
#undef ROUND
  o0 = x0; o1 = x1;
}

__device__ __forceinline__ uint32_t rbits32(uint32_t k0, uint32_t k1, uint32_t i) {
  uint32_t a, b; tf2x32(k0, k1, 0u, i, a, b); return a ^ b;
}
__device__ __forceinline__ float uni01(uint32_t bits) {
  return __uint_as_float((bits >> 9) | 0x3f800000u) - 1.0f;
}

struct Keys { uint32_t k[NB][4][2]; };   // host-precomputed subkeys, by-value kernarg

// ---------------- kernel 1: per-anchor IoU sums (verbatim r9, proven) ----------------
__global__ __launch_bounds__(256) void k_iou(const float* __restrict__ tubes,
                                             const float* __restrict__ gtb,
                                             float* __restrict__ ov) {
  int img = blockIdx.y;
  int a = blockIdx.z;
  int b = blockIdx.x;
  int tid = threadIdx.x;
  int n = b * 256 + tid;
  bool valid = n < MM;
  int nn = valid ? n : MM - 1;
  bool isroi = nn < NROI;

  __shared__ float tub[256 * 7];
  __shared__ float4 g4[NA][T];
  __shared__ float gar[NA][T];
  {
    int rcnt = min(256, NROI - b * 256);       // 256, or 32 for b=78
    int f4cnt = (rcnt * 7) >> 2;
    const float4* src = (const float4*)(tubes + (size_t)img * NROI * 7 + (size_t)b * 256 * 7);
    float4* dst = (float4*)tub;
    for (int i = tid; i < f4cnt; i += 256) dst[i] = src[i];
  }
  for (int i = tid; i < NA * T; i += 256) {
    int aa = i / T, t = i - aa * T;
    const float* p = gtb + (((size_t)img * NA + aa) * T + t) * 5;
    float4 v = make_float4(p[0], p[1], p[2], p[3]);
    g4[aa][t] = v;
    gar[aa][t] = (v.z - v.x + 1.0f) * (v.w - v.y + 1.0f);
  }
  __syncthreads();

  float s = 0.0f;
  if (isroi) {
    const float* p = &tub[tid * 7];
    float rx1 = p[1], ry1 = p[2], rx2 = p[4], ry2 = p[5];
    int sf = (int)rintf(p[3]), ef = (int)rintf(p[6]);
    float rar = (rx2 - rx1 + 1.0f) * (ry2 - ry1 + 1.0f);
#pragma unroll
    for (int t = 0; t < T; ++t) {
      float4 gg = g4[a][t]; float ag = gar[a][t];
      float iw = fmaxf(fminf(rx2, gg.z) - fmaxf(rx1, gg.x) + 1.0f, 0.0f);
      float ih = fmaxf(fminf(ry2, gg.w) - fmaxf(ry1, gg.y) + 1.0f, 0.0f);
      float inter = iw * ih;
      float q = inter / (rar + ag - inter);
      s += ((t >= sf) && (t <= ef)) ? q : 0.0f;   // +0.0 keeps exact sum (verified r2-r9)
    }
  } else {
    int ga = nn - NROI;
#pragma unroll
    for (int t = 0; t < T; ++t) {
      float4 e = g4[ga][t]; float ar = gar[ga][t];
      float4 gg = g4[a][t]; float ag = gar[a][t];
      float iw = fmaxf(fminf(e.z, gg.z) - fmaxf(e.x, gg.x) + 1.0f, 0.0f);
      float ih = fmaxf(fminf(e.w, gg.w) - fmaxf(e.y, gg.y) + 1.0f, 0.0f);
      float inter = iw * ih;
      s += inter / (ar + ag - inter);
    }
  }
  if (valid) ov[((size_t)img * NA + a) * MMPAD + n] = s / 16.0f;
}

// ---------------- kernel 2: classify + compact + sort + sample + outputs, 1 block/image ----------------
#define BITONIC_SORT(ARR, N)                                        \
  for (int k_ = 2; k_ <= (N); k_ <<= 1) {                           \
    for (int j_ = k_ >> 1; j_; j_ >>= 1) {                          \
      for (int i_ = tid; i_ < (N); i_ += 1024) {                    \
        int ixj_ = i_ ^ j_;                                         \
        if (ixj_ > i_) {                                            \
          uint64_t a_ = (ARR)[i_], b_ = (ARR)[ixj_];                \
          bool up_ = (i_ & k_) == 0;                                \
          if (up_ ? (a_ > b_) : (a_ < b_)) {                        \
            (ARR)[i_] = b_; (ARR)[ixj_] = a_;                       \
          }                                                         \
        }                                                           \
      }                                                             \
      __syncthreads();                                              \
    }                                                               \
  }

__global__ __launch_bounds__(1024) void k_finish(const float* __restrict__ tubes,
                                                 const float* __restrict__ gtb,
                                                 const float* __restrict__ gta,
                                                 const float* __restrict__ ov,
                                                 uint64_t* __restrict__ slots,
                                                 Keys keys,
                                                 float* __restrict__ out) {
  int img = blockIdx.x;
  int tid = threadIdx.x;
  int lane = tid & 63;
  int w = tid >> 6;                 // 16 waves

  __shared__ uint64_t bgbuf[BGCAP];       // 64 KiB
  __shared__ uint64_t fgbuf[FGCAP];       // 16 KiB
  __shared__ unsigned char s_asg[MMPAD];  // ~19.75 KiB
  __shared__ int wcnt[16][2];
  __shared__ int s_base[2];
  __shared__ int s_min[2];
  __shared__ int s_keep[RPI];
  __shared__ int s_ak[RPI];
  __shared__ float s_lab[RPI];

  if (tid == 0) { s_base[0] = 0; s_base[1] = 0; s_min[0] = 0x7FFFFFFF; s_min[1] = 0x7FFFFFFF; }
  __syncthreads();

  const float* base_ov = ov + (size_t)img * NA * MMPAD;
  uint64_t* slotF = slots + (size_t)(img * 2 + 0) * SORTCAP;
  uint64_t* slotB = slots + (size_t)(img * 2 + 1) * SORTCAP;
  unsigned long long below = (1ULL << lane) - 1ULL;

  // ---- phase 1: classify + compact (20 chunks of 1024) ----
  for (int c = 0; c < 20; ++c) {
    int n = c * 1024 + tid;
    bool valid = n < MM;
    int nn = valid ? n : MM - 1;
    float o0 = base_ov[0 * MMPAD + nn];
    float o1 = base_ov[1 * MMPAD + nn];
    float o2 = base_ov[2 * MMPAD + nn];
    float o3 = base_ov[3 * MMPAD + nn];
    float o4 = base_ov[4 * MMPAD + nn];
    float best = o0; int barg = 0;
    if (o1 > best) { best = o1; barg = 1; }   // first-max == jnp.argmax
    if (o2 > best) { best = o2; barg = 2; }
    if (o3 > best) { best = o3; barg = 3; }
    if (o4 > best) { best = o4; barg = 4; }
    if (valid) s_asg[n] = (unsigned char)barg;

    bool isfg = valid && (best >= 0.5f);
    bool isbg = valid && (best < 0.5f) && (best >= 0.1f);

    unsigned long long mfg = __ballot(isfg);
    unsigned long long mbg = __ballot(isbg);
    unsigned long long mnf = __ballot(valid && !isfg);
    unsigned long long mnb = __ballot(valid && !isbg);
    int wavebase = c * 1024 + w * 64;
    if (lane == 0) {
      wcnt[w][0] = __popcll(mfg);
      wcnt[w][1] = __popcll(mbg);
      if (mnf) atomicMin(&s_min[0], wavebase + __ffsll(mnf) - 1);
      if (mnb) atomicMin(&s_min[1], wavebase + __ffsll(mnb) - 1);
    }
    __syncthreads();

    int pf = s_base[0], pb = s_base[1];
    for (int w2 = 0; w2 < w; ++w2) { pf += wcnt[w2][0]; pb += wcnt[w2][1]; }
    if (isfg) {
      int pos = pf + __popcll(mfg & below);
      uint32_t m = rbits32(keys.k[img][0][0], keys.k[img][0][1], (uint32_t)n) >> 9;
      uint64_t key = ((uint64_t)m << 32) | (uint32_t)n;
      if (pos < FGCAP) fgbuf[pos] = key;
      slotF[pos] = key;                      // mirror for overflow fallback
    }
    if (isbg) {
      int pos = pb + __popcll(mbg & below);
      uint32_t m = rbits32(keys.k[img][1][0], keys.k[img][1][1], (uint32_t)n) >> 9;
      uint64_t key = ((uint64_t)m << 32) | (uint32_t)n;
      if (pos < BGCAP) bgbuf[pos] = key;
      slotB[pos] = key;
    }
    __syncthreads();
    if (tid == 0) {
      int tf = 0, tb = 0;
      for (int w2 = 0; w2 < 16; ++w2) { tf += wcnt[w2][0]; tb += wcnt[w2][1]; }
      s_base[0] += tf; s_base[1] += tb;
    }
    __syncthreads();
  }

  int fg_num = s_base[0], bg_num = s_base[1];
  int min_nonfg = s_min[0], min_nonbg = s_min[1];
  bool fgLds = fg_num <= FGCAP;
  bool bgLds = bg_num <= BGCAP;

  // ---- phase 2: sort each list (LDS fast path, global fallback) ----
  if (fg_num > 1) {
    int nf = 2; while (nf < fg_num) nf <<= 1;
    if (fgLds) {
      for (int i = fg_num + tid; i < nf; i += 1024) fgbuf[i] = ~0ULL;
      __syncthreads();
      BITONIC_SORT(fgbuf, nf)
    } else {
      for (int i = fg_num + tid; i < nf; i += 1024) slotF[i] = ~0ULL;
      __syncthreads();
      BITONIC_SORT(slotF, nf)
    }
  }
  if (bg_num > 1) {
    int nb2 = 2; while (nb2 < bg_num) nb2 <<= 1;
    if (bgLds) {
      for (int i = bg_num + tid; i < nb2; i += 1024) bgbuf[i] = ~0ULL;
      __syncthreads();
      BITONIC_SORT(bgbuf, nb2)
    } else {
      for (int i = bg_num + tid; i < nb2; i += 1024) slotB[i] = ~0ULL;
      __syncthreads();
      BITONIC_SORT(slotB, nb2)
    }
  }
  __syncthreads();

  // ---- phase 3: sampling (proven r9 logic) ----
  float* o_rois = out;
  float* o_tub = out + (size_t)NB * RPI * 65;
  float* o_lab = o_tub + (size_t)NB * RPI * 7;
  float* o_tgt = o_lab + (size_t)NB * RPI;
  float* o_in  = o_tgt + (size_t)NB * RPI * 64;
  float* o_ou  = o_in  + (size_t)NB * RPI * 64;

  if (tid < RPI) {
    int r = tid;
    float u3 = uni01(rbits32(keys.k[img][2][0], keys.k[img][2][1], (uint32_t)r));
    float u4 = uni01(rbits32(keys.k[img][3][0], keys.k[img][3][1], (uint32_t)r));

    int fg_this = (bg_num > 0) ? min(FGPI, fg_num) : (fg_num > 0 ? RPI : 0);

#define FG_AT(i) (fgLds ? (int)(uint32_t)(fgbuf[i] & 0xffffffffULL) : (int)(uint32_t)(slotF[i] & 0xffffffffULL))
#define BG_AT(i) (bgLds ? (int)(uint32_t)(bgbuf[i] & 0xffffffffULL) : (int)(uint32_t)(slotB[i] & 0xffffffffULL))

    int fg_idx;
    if (bg_num > 0) {
      fg_idx = FG_AT(r);                      // only used for r < fg_this <= 32
    } else {
      int q = (int)(u3 * (float)max(fg_num, 1));
      fg_idx = (q >= fg_num)
                 ? ((fg_num >= MM) ? FG_AT(MM - 1) : min_nonfg)
                 : FG_AT(q);
    }
    int qb = (int)(u4 * (float)max(bg_num, 1));
    int bg_idx = (qb >= bg_num)
                   ? ((bg_num >= MM) ? BG_AT(MM - 1) : min_nonbg)
                   : BG_AT(qb);
#undef FG_AT
#undef BG_AT

    bool is_fg = r < fg_this;
    int keep = is_fg ? fg_idx : bg_idx;
    int ak = s_asg[keep];
    float glab = gtb[(((size_t)img * NA + ak) * T + 0) * 5 + 4];
    float lab = is_fg ? glab : 0.0f;

    s_keep[r] = keep; s_ak[r] = ak; s_lab[r] = lab;

    size_t row = (size_t)img * RPI + r;
    float* pt = o_tub + row * 7;
    o_rois[row * 65] = (float)img;
    pt[0] = (float)img;
    if (keep < NROI) {
      const float* p = tubes + ((size_t)img * NROI + keep) * 7;
#pragma unroll
      for (int cc = 1; cc < 7; ++cc) pt[cc] = p[cc];
    } else {
      const float* p = gta + ((size_t)img * NA + (keep - NROI)) * 7;
#pragma unroll
      for (int cc = 1; cc < 7; ++cc) pt[cc] = p[cc - 1];
    }
    o_lab[row] = lab;
  }
  __syncthreads();

  // ---- phase 4: per-(row,frame) outputs ----
  for (int i = tid; i < RPI * T; i += 1024) {
    int rl = i >> 4;
    int t = i & 15;
    size_t row = (size_t)img * RPI + rl;
    int keep = s_keep[rl];
    int ak = s_ak[rl];
    float lab = s_lab[rl];
    bool pos = lab > 0.0f;
    float posf = pos ? 1.0f : 0.0f;

    float ex1, ey1, ex2, ey2;
    if (keep < NROI) {
      const float* p = tubes + ((size_t)img * NROI + keep) * 7;
      int sf = (int)rintf(p[3]), ef = (int)rintf(p[6]);
      bool in = (t >= sf) && (t <= ef);
      ex1 = in ? p[1] : 0.0f; ey1 = in ? p[2] : 0.0f;
      ex2 = in ? p[4] : 0.0f; ey2 = in ? p[5] : 0.0f;
    } else {
      const float* p = gtb + (((size_t)img * NA + (keep - NROI)) * T + t) * 5;
      ex1 = p[0]; ey1 = p[1]; ex2 = p[2]; ey2 = p[3];
    }

    float* pr = o_rois + row * 65 + 1 + 4 * t;
    pr[0] = ex1; pr[1] = ey1; pr[2] = ex2; pr[3] = ey2;

    const float* gp = gtb + (((size_t)img * NA + ak) * T + t) * 5;
    float gx1 = gp[0], gy1 = gp[1], gx2 = gp[2], gy2 = gp[3];
    float ew = ex2 - ex1 + 1.0f, eh = ey2 - ey1 + 1.0f;
    float ecx = ex1 + 0.5f * ew, ecy = ey1 + 0.5f * eh;
    float gw = gx2 - gx1 + 1.0f, gh = gy2 - gy1 + 1.0f;
    float gcx = gx1 + 0.5f * gw, gcy = gy1 + 0.5f * gh;
    float t0 = ((gcx - ecx) / ew) / 0.1f;
    float t1 = ((gcy - ecy) / eh) / 0.1f;
    float t2 = logf(gw / ew) / 0.2f;
    float t3 = logf(gh / eh) / 0.2f;

    *(float4*)(o_tgt + row * 64 + 4 * t) =
        make_float4(pos ? t0 : 0.0f, pos ? t1 : 0.0f, pos ? t2 : 0.0f, pos ? t3 : 0.0f);
    float4 pf4 = make_float4(posf, posf, posf, posf);
    *(float4*)(o_in + row * 64 + 4 * t) = pf4;
    *(float4*)(o_ou + row * 64 + 4 * t) = pf4;
  }
}

extern "C" void kernel_launch(void* const* d_in, const int* in_sizes, int n_in,
                              void* d_out, int out_size, void* d_ws, size_t ws_size,
                              hipStream_t stream) {
  const float* tubes = (const float*)d_in[0];       // [8][20000][7]
  const float* gtb   = (const float*)d_in[1];       // [8][5][16][5]
  const float* gta   = (const float*)d_in[2];       // [8][5][7]
  float* out = (float*)d_out;
  char* ws = (char*)d_ws;

  // host-side key derivation (pure, deterministic): key(42)=(0,42); foldlike splits
  Keys keys;
  for (int img = 0; img < NB; ++img) {
    uint32_t r0, r1; tf2x32(0u, 42u, 0u, (uint32_t)img, r0, r1);
    for (int j = 0; j < 4; ++j) {
      uint32_t a, b; tf2x32(r0, r1, 0u, (uint32_t)j, a, b);
      keys.k[img][j][0] = a; keys.k[img][j][1] = b;
    }
  }

  // workspace layout
  uint64_t* slots = (uint64_t*)ws;                 // 2*8*32768*8 = 4,194,304
  float* ov = (float*)(ws + 4194304);              // 8*5*20224*4 = 3,235,840 -> ends 7,430,144
  // total = 7,430,144 bytes

  dim3 gI(NBLK, NB, NA);
  k_iou<<<gI, 256, 0, stream>>>(tubes, gtb, ov);
  k_finish<<<NB, 1024, 0, stream>>>(tubes, gtb, gta, ov, slots, keys, out);
}

// Round 11
// 48.646 us; speedup vs baseline: 1.6312x; 1.6312x over previous
//
#include <hip/hip_runtime.h>
#include <stdint.h>

#define T 16
#define NB 8
#define NROI 20000
#define NA 5
#define MM (NROI + NA)   // 20005
#define MMPAD 20224      // NBLK*256, per-(img,a) ov stride
#define RPI 128
#define FGPI 32
#define NBLK 79          // blocks per image in k_iou
#define NBLK2 20         // 1024-thread blocks per image in k_classify
#define SORTCAP 32768
#define CSTRIDE 32       // ints per image in counts (128B line padding)

// ---------------- threefry2x32 (JAX-exact, 20 rounds), host+device ----------------
__host__ __device__ __forceinline__ void tf2x32(uint32_t k0, uint32_t k1,
                                                uint32_t x0, uint32_t x1,
                                                uint32_t& o0, uint32_t& o1) {
  uint32_t ks2 = k0 ^ k1 ^ 0x1BD11BDAu;
  x0 += k0; x1 += k1;
#define ROUND(r) { x0 += x1; x1 = (x1 << (r)) | (x1 >> (32 - (r))); x1 ^= x0; }
  ROUND(13) ROUND(15) ROUND(26) ROUND(6)
  x0 += k1; x1 += ks2 + 1u;
  ROUND(17) ROUND(29) ROUND(16) ROUND(24)
  x0 += ks2; x1 += k0 + 2u;
  ROUND(13) ROUND(15) ROUND(26) ROUND(6)
  x0 += k0; x1 += k1 + 3u;
  ROUND(17) ROUND(29) ROUND(16) ROUND(24)
  x0 += k1; x1 += ks2 + 4u;
  ROUND(13) ROUND(15) ROUND(26) ROUND(6)
  x0 += ks2; x1 += k0 + 5u;
#undef ROUND
  o0 = x0; o1 = x1;
}

__device__ __forceinline__ uint32_t rbits32(uint32_t k0, uint32_t k1, uint32_t i) {
  uint32_t a, b; tf2x32(k0, k1, 0u, i, a, b); return a ^ b;
}
__device__ __forceinline__ float uni01(uint32_t bits) {
  return __uint_as_float((bits >> 9) | 0x3f800000u) - 1.0f;
}

struct Keys { uint32_t k[NB][4][2]; };   // host-precomputed subkeys, by-value kernarg

// ---------------- kernel 1: per-anchor IoU sums (verbatim r9, proven) ----------------
__global__ __launch_bounds__(256) void k_iou(const float* __restrict__ tubes,
                                             const float* __restrict__ gtb,
                                             float* __restrict__ ov) {
  int img = blockIdx.y;
  int a = blockIdx.z;
  int b = blockIdx.x;
  int tid = threadIdx.x;
  int n = b * 256 + tid;
  bool valid = n < MM;
  int nn = valid ? n : MM - 1;
  bool isroi = nn < NROI;

  __shared__ float tub[256 * 7];
  __shared__ float4 g4[NA][T];
  __shared__ float gar[NA][T];
  {
    int rcnt = min(256, NROI - b * 256);       // 256, or 32 for b=78
    int f4cnt = (rcnt * 7) >> 2;
    const float4* src = (const float4*)(tubes + (size_t)img * NROI * 7 + (size_t)b * 256 * 7);
    float4* dst = (float4*)tub;
    for (int i = tid; i < f4cnt; i += 256) dst[i] = src[i];
  }
  for (int i = tid; i < NA * T; i += 256) {
    int aa = i / T, t = i - aa * T;
    const float* p = gtb + (((size_t)img * NA + aa) * T + t) * 5;
    float4 v = make_float4(p[0], p[1], p[2], p[3]);
    g4[aa][t] = v;
    gar[aa][t] = (v.z - v.x + 1.0f) * (v.w - v.y + 1.0f);
  }
  __syncthreads();

  float s = 0.0f;
  if (isroi) {
    const float* p = &tub[tid * 7];
    float rx1 = p[1], ry1 = p[2], rx2 = p[4], ry2 = p[5];
    int sf = (int)rintf(p[3]), ef = (int)rintf(p[6]);
    float rar = (rx2 - rx1 + 1.0f) * (ry2 - ry1 + 1.0f);
#pragma unroll
    for (int t = 0; t < T; ++t) {
      float4 gg = g4[a][t]; float ag = gar[a][t];
      float iw = fmaxf(fminf(rx2, gg.z) - fmaxf(rx1, gg.x) + 1.0f, 0.0f);
      float ih = fmaxf(fminf(ry2, gg.w) - fmaxf(ry1, gg.y) + 1.0f, 0.0f);
      float inter = iw * ih;
      float q = inter / (rar + ag - inter);
      s += ((t >= sf) && (t <= ef)) ? q : 0.0f;   // +0.0 keeps exact sum (verified r2-r10)
    }
  } else {
    int ga = nn - NROI;
#pragma unroll
    for (int t = 0; t < T; ++t) {
      float4 e = g4[ga][t]; float ar = gar[ga][t];
      float4 gg = g4[a][t]; float ag = gar[a][t];
      float iw = fmaxf(fminf(e.z, gg.z) - fmaxf(e.x, gg.x) + 1.0f, 0.0f);
      float ih = fmaxf(fminf(e.w, gg.w) - fmaxf(e.y, gg.y) + 1.0f, 0.0f);
      float inter = iw * ih;
      s += inter / (ar + ag - inter);
    }
  }
  if (valid) ov[((size_t)img * NA + a) * MMPAD + n] = s / 16.0f;
}

// ---------------- kernel 2: argmax + classify + compaction (1024-thread blocks) ----------------
__global__ __launch_bounds__(1024) void k_classify(const float* __restrict__ ov,
                                                   unsigned char* __restrict__ asg,
                                                   uint64_t* __restrict__ slots,
                                                   int* __restrict__ cnts2,
                                                   int* __restrict__ mins2,
                                                   Keys keys) {
  int img = blockIdx.y;
  int b = blockIdx.x;             // 0..19
  int tid = threadIdx.x;
  int n = b * 1024 + tid;
  bool valid = n < MM;
  int nn = valid ? n : MM - 1;
  int lane = tid & 63;
  int w = tid >> 6;               // 16 waves

  const float* base_ov = ov + (size_t)img * NA * MMPAD + nn;
  float o0 = base_ov[0 * MMPAD];
  float o1 = base_ov[1 * MMPAD];
  float o2 = base_ov[2 * MMPAD];
  float o3 = base_ov[3 * MMPAD];
  float o4 = base_ov[4 * MMPAD];
  float best = o0; int barg = 0;
  if (o1 > best) { best = o1; barg = 1; }       // first-max == jnp.argmax
  if (o2 > best) { best = o2; barg = 2; }
  if (o3 > best) { best = o3; barg = 3; }
  if (o4 > best) { best = o4; barg = 4; }

  if (valid) asg[(size_t)img * MM + n] = (unsigned char)barg;

  bool isfg = valid && (best >= 0.5f);
  bool isbg = valid && (best < 0.5f) && (best >= 0.1f);

  __shared__ int wcnt[16][2];
  __shared__ int wmn[16][2];
  unsigned long long mfg = __ballot(isfg);
  unsigned long long mbg = __ballot(isbg);
  unsigned long long mnf = __ballot(valid && !isfg);
  unsigned long long mnb = __ballot(valid && !isbg);
  int wavebase = b * 1024 + w * 64;
  if (lane == 0) {
    wcnt[w][0] = __popcll(mfg);
    wcnt[w][1] = __popcll(mbg);
    wmn[w][0] = mnf ? (wavebase + __ffsll(mnf) - 1) : 0x7FFFFFFF;
    wmn[w][1] = mnb ? (wavebase + __ffsll(mnb) - 1) : 0x7FFFFFFF;
  }
  __syncthreads();

  if (tid == 0) {
    int tf = 0, tb = 0, mf = 0x7FFFFFFF, mb = 0x7FFFFFFF;
#pragma unroll
    for (int w2 = 0; w2 < 16; ++w2) {
      tf += wcnt[w2][0]; tb += wcnt[w2][1];
      mf = min(mf, wmn[w2][0]); mb = min(mb, wmn[w2][1]);
    }
    int idx = img * NBLK2 + b;
    cnts2[idx]                = tf;
    cnts2[NB * NBLK2 + idx]   = tb;
    mins2[idx]                = mf;
    mins2[NB * NBLK2 + idx]   = mb;
  }

  int pf = 0, pb = 0;
  for (int w2 = 0; w2 < w; ++w2) { pf += wcnt[w2][0]; pb += wcnt[w2][1]; }
  unsigned long long below = (1ULL << lane) - 1ULL;
  uint64_t* slotF = slots + (size_t)(img * 2 + 0) * SORTCAP + b * 1024;
  uint64_t* slotB = slots + (size_t)(img * 2 + 1) * SORTCAP + b * 1024;
  if (isfg) {
    int pos = pf + __popcll(mfg & below);
    uint32_t m = rbits32(keys.k[img][0][0], keys.k[img][0][1], (uint32_t)n) >> 9;
    slotF[pos] = ((uint64_t)m << 32) | (uint32_t)n;
  }
  if (isbg) {
    int pos = pb + __popcll(mbg & below);
    uint32_t m = rbits32(keys.k[img][1][0], keys.k[img][1][1], (uint32_t)n) >> 9;
    slotB[pos] = ((uint64_t)m << 32) | (uint32_t)n;
  }
}

// ---------------- kernel 3: scan (LDS-staged) + gather + bitonic sort ----------------
__global__ __launch_bounds__(1024) void k_sort(uint64_t* __restrict__ slots,
                                               const int* __restrict__ cnts2,
                                               const int* __restrict__ mins2,
                                               int* __restrict__ counts) {
  __shared__ uint64_t buf[8192];   // 64 KiB
  __shared__ int scnt[NBLK2], spref[NBLK2 + 1], smn[NBLK2];
  __shared__ int stot;
  int list = blockIdx.x;           // (img<<1)|which
  int img = list >> 1;
  int which = list & 1;
  int tid = threadIdx.x;
  uint64_t* arr = slots + (size_t)(img * 2 + which) * SORTCAP;
  const int* cn = cnts2 + which * NB * NBLK2 + img * NBLK2;
  const int* mn = mins2 + which * NB * NBLK2 + img * NBLK2;

  if (tid < NBLK2) { scnt[tid] = cn[tid]; smn[tid] = mn[tid]; }
  __syncthreads();
  if (tid == 0) {
    int acc = 0, mmn = 0x7FFFFFFF;
#pragma unroll
    for (int bb = 0; bb < NBLK2; ++bb) {
      spref[bb] = acc; acc += scnt[bb]; mmn = min(mmn, smn[bb]);
    }
    spref[NBLK2] = acc; stot = acc;
    counts[img * CSTRIDE + which] = acc;        // fg_num / bg_num
    counts[img * CSTRIDE + 2 + which] = mmn;    // min_nonfg / min_nonbg (raw index)
  }
  __syncthreads();
  int cnt = stot;
  if (cnt == 0) return;
  int n = 2; while (n < cnt) n <<= 1;

  if (n <= 8192) {
    for (int s = tid; s < NBLK2 * 1024; s += 1024) {
      int bb = s >> 10, i = s & 1023;
      if (i < scnt[bb]) buf[spref[bb] + i] = arr[s];
    }
    for (int i = cnt + tid; i < n; i += 1024) buf[i] = ~0ULL;
    __syncthreads();
    for (int k = 2; k <= n; k <<= 1) {
      for (int j = k >> 1; j; j >>= 1) {
        for (int i = tid; i < n; i += 1024) {
          int ixj = i ^ j;
          if (ixj > i) {
            uint64_t a = buf[i], bv = buf[ixj];
            bool up = (i & k) == 0;
            if (up ? (a > bv) : (a < bv)) { buf[i] = bv; buf[ixj] = a; }
          }
        }
        __syncthreads();
      }
    }
    for (int i = tid; i < cnt; i += 1024) arr[i] = buf[i];
  } else {
    // in-place left-compaction, serial by segment (dest never clobbers unread src)
    for (int bb = 0; bb < NBLK2; ++bb) {
      uint64_t v = 0; int c = scnt[bb];
      if (tid < c) v = arr[bb * 1024 + tid];
      __syncthreads();
      if (tid < c) arr[spref[bb] + tid] = v;
      __syncthreads();
    }
    for (int i = cnt + tid; i < n; i += 1024) arr[i] = ~0ULL;
    __syncthreads();
    for (int k = 2; k <= n; k <<= 1) {
      for (int j = k >> 1; j; j >>= 1) {
        for (int i = tid; i < n; i += 1024) {
          int ixj = i ^ j;
          if (ixj > i) {
            uint64_t a = arr[i], bv = arr[ixj];
            bool up = (i & k) == 0;
            if (up ? (a > bv) : (a < bv)) { arr[i] = bv; arr[ixj] = a; }
          }
        }
        __syncthreads();
      }
    }
  }
}

// ---------------- kernel 4: fused sampling + all outputs (1 block / image) ----------------
__global__ __launch_bounds__(256) void k_sample(const float* __restrict__ tubes,
                                                const float* __restrict__ gtb,
                                                const float* __restrict__ gta,
                                                const unsigned char* __restrict__ asg,
                                                const uint64_t* __restrict__ slots,
                                                const int* __restrict__ counts,
                                                Keys keys,
                                                float* __restrict__ out) {
  int img = blockIdx.x;
  int tid = threadIdx.x;
  __shared__ int s_keep[RPI];
  __shared__ int s_ak[RPI];
  __shared__ float s_lab[RPI];

  float* o_rois = out;
  float* o_tub = out + (size_t)NB * RPI * 65;
  float* o_lab = o_tub + (size_t)NB * RPI * 7;
  float* o_tgt = o_lab + (size_t)NB * RPI;
  float* o_in  = o_tgt + (size_t)NB * RPI * 64;
  float* o_ou  = o_in  + (size_t)NB * RPI * 64;

  if (tid < RPI) {
    int r = tid;
    int cb = img * CSTRIDE;
    int fg_num = counts[cb + 0], bg_num = counts[cb + 1];
    int min_nonfg = counts[cb + 2];
    int min_nonbg = counts[cb + 3];

    float u3 = uni01(rbits32(keys.k[img][2][0], keys.k[img][2][1], (uint32_t)r));
    float u4 = uni01(rbits32(keys.k[img][3][0], keys.k[img][3][1], (uint32_t)r));

    int fg_this = (bg_num > 0) ? min(FGPI, fg_num) : (fg_num > 0 ? RPI : 0);
    const uint64_t* fga = slots + (size_t)(img * 2 + 0) * SORTCAP;
    const uint64_t* bga = slots + (size_t)(img * 2 + 1) * SORTCAP;

    int fg_idx;
    if (bg_num > 0) {
      fg_idx = (int)(uint32_t)(fga[r] & 0xffffffffULL);
    } else {
      int q = (int)(u3 * (float)max(fg_num, 1));
      fg_idx = (q >= fg_num)
                 ? ((fg_num >= MM) ? (int)(uint32_t)(fga[MM - 1] & 0xffffffffULL) : min_nonfg)
                 : (int)(uint32_t)(fga[q] & 0xffffffffULL);
    }
    int qb = (int)(u4 * (float)max(bg_num, 1));
    int bg_idx = (qb >= bg_num)
                   ? ((bg_num >= MM) ? (int)(uint32_t)(bga[MM - 1] & 0xffffffffULL) : min_nonbg)
                   : (int)(uint32_t)(bga[qb] & 0xffffffffULL);

    bool is_fg = r < fg_this;
    int keep = is_fg ? fg_idx : bg_idx;
    int ak = asg[(size_t)img * MM + keep];
    float glab = gtb[(((size_t)img * NA + ak) * T + 0) * 5 + 4];
    float lab = is_fg ? glab : 0.0f;

    s_keep[r] = keep; s_ak[r] = ak; s_lab[r] = lab;

    size_t row = (size_t)img * RPI + r;
    float* pt = o_tub + row * 7;
    o_rois[row * 65] = (float)img;
    pt[0] = (float)img;
    if (keep < NROI) {
      const float* p = tubes + ((size_t)img * NROI + keep) * 7;
#pragma unroll
      for (int c = 1; c < 7; ++c) pt[c] = p[c];
    } else {
      const float* p = gta + ((size_t)img * NA + (keep - NROI)) * 7;
#pragma unroll
      for (int c = 1; c < 7; ++c) pt[c] = p[c - 1];
    }
    o_lab[row] = lab;
  }
  __syncthreads();

  for (int i = tid; i < RPI * T; i += 256) {
    int rl = i >> 4;
    int t = i & 15;
    size_t row = (size_t)img * RPI + rl;
    int keep = s_keep[rl];
    int ak = s_ak[rl];
    float lab = s_lab[rl];
    bool pos = lab > 0.0f;
    float posf = pos ? 1.0f : 0.0f;

    float ex1, ey1, ex2, ey2;
    if (keep < NROI) {
      const float* p = tubes + ((size_t)img * NROI + keep) * 7;
      int sf = (int)rintf(p[3]), ef = (int)rintf(p[6]);
      bool in = (t >= sf) && (t <= ef);
      ex1 = in ? p[1] : 0.0f; ey1 = in ? p[2] : 0.0f;
      ex2 = in ? p[4] : 0.0f; ey2 = in ? p[5] : 0.0f;
    } else {
      const float* p = gtb + (((size_t)img * NA + (keep - NROI)) * T + t) * 5;
      ex1 = p[0]; ey1 = p[1]; ex2 = p[2]; ey2 = p[3];
    }

    float* pr = o_rois + row * 65 + 1 + 4 * t;
    pr[0] = ex1; pr[1] = ey1; pr[2] = ex2; pr[3] = ey2;

    const float* gp = gtb + (((size_t)img * NA + ak) * T + t) * 5;
    float gx1 = gp[0], gy1 = gp[1], gx2 = gp[2], gy2 = gp[3];
    float ew = ex2 - ex1 + 1.0f, eh = ey2 - ey1 + 1.0f;
    float ecx = ex1 + 0.5f * ew, ecy = ey1 + 0.5f * eh;
    float gw = gx2 - gx1 + 1.0f, gh = gy2 - gy1 + 1.0f;
    float gcx = gx1 + 0.5f * gw, gcy = gy1 + 0.5f * gh;
    float t0 = ((gcx - ecx) / ew) / 0.1f;
    float t1 = ((gcy - ecy) / eh) / 0.1f;
    float t2 = logf(gw / ew) / 0.2f;
    float t3 = logf(gh / eh) / 0.2f;

    *(float4*)(o_tgt + row * 64 + 4 * t) =
        make_float4(pos ? t0 : 0.0f, pos ? t1 : 0.0f, pos ? t2 : 0.0f, pos ? t3 : 0.0f);
    float4 pf4 = make_float4(posf, posf, posf, posf);
    *(float4*)(o_in + row * 64 + 4 * t) = pf4;
    *(float4*)(o_ou + row * 64 + 4 * t) = pf4;
  }
}

extern "C" void kernel_launch(void* const* d_in, const int* in_sizes, int n_in,
                              void* d_out, int out_size, void* d_ws, size_t ws_size,
                              hipStream_t stream) {
  const float* tubes = (const float*)d_in[0];       // [8][20000][7]
  const float* gtb   = (const float*)d_in[1];       // [8][5][16][5]
  const float* gta   = (const float*)d_in[2];       // [8][5][7]
  float* out = (float*)d_out;
  char* ws = (char*)d_ws;

  // host-side key derivation (pure, deterministic): key(42)=(0,42); foldlike splits
  Keys keys;
  for (int img = 0; img < NB; ++img) {
    uint32_t r0, r1; tf2x32(0u, 42u, 0u, (uint32_t)img, r0, r1);
    for (int j = 0; j < 4; ++j) {
      uint32_t a, b; tf2x32(r0, r1, 0u, (uint32_t)j, a, b);
      keys.k[img][j][0] = a; keys.k[img][j][1] = b;
    }
  }

  // workspace layout
  int* counts = (int*)ws;                              // 1024 B
  int* cnts2  = (int*)(ws + 1024);                     // 2*8*20*4 = 1280 -> ends 2304
  int* mins2  = (int*)(ws + 2304);                     // 1280 -> ends 3584
  unsigned char* asg = (unsigned char*)(ws + 3584);    // 160040 -> ends 163624
  uint64_t* slots = (uint64_t*)(ws + 163624);          // 163624 % 8 == 0; 4,194,304 -> ends 4,357,928
  float* ov = (float*)(ws + 4357928);                  // 3,235,840 -> ends 7,593,768
  // total = 7,593,768 bytes

  dim3 gI(NBLK, NB, NA);
  k_iou<<<gI, 256, 0, stream>>>(tubes, gtb, ov);
  dim3 gC(NBLK2, NB);
  k_classify<<<gC, 1024, 0, stream>>>(ov, asg, slots, cnts2, mins2, keys);
  k_sort<<<16, 1024, 0, stream>>>(slots, cnts2, mins2, counts);
  k_sample<<<NB, 256, 0, stream>>>(tubes, gtb, gta, asg, slots, counts, keys, out);
}